// Round 5
// baseline (291.200 us; speedup 1.0000x reference)
//
#include <hip/hip_runtime.h>
#include <math.h>

// Problem constants
#define BQ 64
#define NOBJ 5
#define CIN 3
#define IMG_H 64
#define IMG_W 96
#define OH 32
#define OW 48
#define NPAIR 25
#define PP 4
#define CONV_OUT 32

// Tiling: each block = (src, b, rowgroup of 2 output rows); 256 threads = 4 waves.
// Each wave handles TWO oc-tiles (mt = wave, wave+4) against the same LDS tile.
#define NRG 16                          // 32 output rows / 2
#define NPOS 96                          // 2 output rows x 48 cols
#define XK 32                           // padded K (27 real + bias + zeros)
#define X_U32 (NOBJ * NPOS * XK / 2)    // 7680 u32 = 30.7 KB (f16 im2col)
#define X_UNITS (NOBJ * NPOS * 4)       // 1920 8-elem units

#define NPRED (2 * 1600 * PP)           // 12800
#define ADJ_N (BQ * 1600)               // 102400

typedef __fp16   h2 __attribute__((ext_vector_type(2)));     // cvt_pkrtz result type
typedef _Float16 half4_t __attribute__((ext_vector_type(4)));// reduce-MFMA A/B operand
typedef _Float16 half8 __attribute__((ext_vector_type(8)));  // conv-MFMA A/B operand
typedef float    float4_ __attribute__((ext_vector_type(4)));
typedef float    float2_ __attribute__((ext_vector_type(2)));
typedef unsigned int uint4_ __attribute__((ext_vector_type(4)));

struct h2x2 { h2 lo, hi; };             // 2x h2 -> bit_cast -> half4_t

// One oc-tile (mt): conv MFMAs + fused relu-combine + reduce-MFMA over all
// 25 pairs in a single pass (25 float4 accumulators, all statically indexed).
__device__ __forceinline__ void run_mt(
    const unsigned int* __restrict__ sX32,
    const float* __restrict__ conv_w,
    const float* __restrict__ conv_b,
    const float* __restrict__ w2,
    float* __restrict__ T,
    int mt, int quad, int ocl, int lane, size_t tbase)
{
    const float4_ zero4 = {0.f, 0.f, 0.f, 0.f};
    const h2 hz = {(__fp16)0.f, (__fp16)0.f};

    const int p   = mt >> 1;
    const int row = mt * 16 + ocl;  // this lane's conv_w row (oc)

    half8 wa, wb;
    #pragma unroll
    for (int j = 0; j < 8; ++j) {
        int k = quad * 8 + j;
        float va = 0.f, vb = 0.f;
        if (k < 27) {
            va = conv_w[row * 54 + k];
            vb = conv_w[row * 54 + 27 + k];
        } else if (k == 27) {
            va = conv_b[row];       // bias pairs with 1.0 lane in X
        }
        wa[j] = (_Float16)va;
        wb[j] = (_Float16)vb;
    }
    // B-operand of the reduce-MFMA: B[k=oc_local][n] = w2[oc], same for all n.
    // 16x16x16 B layout: lane holds k = quad*4 + j  -> exactly wp[0..3].
    half4_t w2f;
    {
        const float* wp = w2 + p * CONV_OUT + (mt & 1) * 16 + quad * 4;
        h2x2 pk;
        pk.lo = __builtin_amdgcn_cvt_pkrtz(wp[0], wp[1]);
        pk.hi = __builtin_amdgcn_cvt_pkrtz(wp[2], wp[3]);
        w2f = __builtin_bit_cast(half4_t, pk);
    }

    float4_ acc2[NPAIR];
    #pragma unroll
    for (int q = 0; q < NPAIR; ++q) acc2[q] = zero4;

    #pragma unroll
    for (int nt = 0; nt < 6; ++nt) {    // 2 rows x 3 col-tiles of 16
        const int rl  = nt / 3;
        const int c0  = (nt - rl * 3) * 16;
        const int pos = rl * 48 + c0 + ocl;
        const int sw  = (pos >> 1) & 3;
        const int sbase = pos * 16 + ((quad ^ sw) << 2);

        half8 xf[NOBJ];
        #pragma unroll
        for (int obj = 0; obj < NOBJ; ++obj)
            xf[obj] = *(const half8*)&sX32[sbase + obj * (NPOS * 16)];

        h2 ah01[NOBJ], ah23[NOBJ];
        #pragma unroll
        for (int ii = 0; ii < NOBJ; ++ii) {
            float4_ a = __builtin_amdgcn_mfma_f32_16x16x32_f16(wa, xf[ii], zero4, 0, 0, 0);
            ah01[ii] = __builtin_amdgcn_cvt_pkrtz(a[0], a[1]);
            ah23[ii] = __builtin_amdgcn_cvt_pkrtz(a[2], a[3]);
        }

        #pragma unroll
        for (int jo = 0; jo < NOBJ; ++jo) {
            float4_ bqv = __builtin_amdgcn_mfma_f32_16x16x32_f16(wb, xf[jo], zero4, 0, 0, 0);
            h2 bh01 = __builtin_amdgcn_cvt_pkrtz(bqv[0], bqv[1]);
            h2 bh23 = __builtin_amdgcn_cvt_pkrtz(bqv[2], bqv[3]);
            #pragma unroll
            for (int ii = 0; ii < NOBJ; ++ii) {
                // relu(a_i + b_j) stays in the exact A-layout of
                // mfma_f32_16x16x16f16 (m = pos = lane&15, k = oc = quad*4+j):
                // one MFMA does the w2-dot over oc AND the pos partial sum,
                // accumulating across nt in C.
                h2 s0 = __builtin_elementwise_max(ah01[ii] + bh01, hz);   // v_pk_add + v_pk_max
                h2 s1 = __builtin_elementwise_max(ah23[ii] + bh23, hz);
                h2x2 pk; pk.lo = s0; pk.hi = s1;
                half4_t a2 = __builtin_bit_cast(half4_t, pk);
                acc2[ii * NOBJ + jo] =
                    __builtin_amdgcn_mfma_f32_16x16x16f16(a2, w2f, acc2[ii * NOBJ + jo], 0, 0, 0);
            }
        }
    }

    // Reduce: lane's 4 regs = 4 pos-rows of its quad (identical across cols),
    // so sum regs then butterfly across quads only (xor 16, 32).
    float pairval = 0.f;
    #pragma unroll
    for (int q = 0; q < NPAIR; ++q) {
        float4_ d = acc2[q];
        float r = (d[0] + d[1]) + (d[2] + d[3]);
        r += __shfl_xor(r, 16, 64);
        r += __shfl_xor(r, 32, 64);
        if (lane == q) pairval = r;
    }

    if (lane < NPAIR)
        T[tbase + (size_t)lane * 8 + mt] = pairval;
}

// T[src][b][rg][pair][mt]; mt = 16-oc tile 0..7 (p = mt>>1). Fully written,
// no memset, no atomics. src==1 blocks also write the adj mask.
// launch_bounds(256,3): both known interpretations of the 2nd arg (blocks/CU
// or waves/EU) give a ~170-VGPR cap and 3 resident blocks/CU -> staging of
// one block overlaps compute of the other two. (Round 2/3 lesson: (512,4)
// behaved as 4 blocks/CU -> 64-VGPR cap -> 448 MB scratch spill.)
__global__ __launch_bounds__(256, 3) void conv_pair_mfma(
    const float* __restrict__ state,
    const float* __restrict__ state_next,
    const float* __restrict__ conv_w,
    const float* __restrict__ conv_b,
    const float* __restrict__ w2,
    float* __restrict__ T,
    float* __restrict__ out)
{
    __shared__ __align__(16) unsigned int sX32[X_U32];   // 30.7 KB f16 im2col

    const int tid = threadIdx.x;
    const int rg  = blockIdx.x;     // 0..15
    const int b   = blockIdx.y;     // 0..63
    const int src = blockIdx.z;     // 0..1

    const float* g = (src == 0 ? state : state_next)
                   + (size_t)b * NOBJ * CIN * IMG_H * IMG_W;
    const int R0 = rg * 4;          // first input row of this rowgroup

    // ---- adj mask from src==1 blocks (independent; pre-barrier) ----
    if (src == 1 && tid < 100) {
        int a  = (rg + NRG * b) * 100 + tid;     // 1024 blocks x 100 = 102400
        int bb = a / 1600;
        int t  = a - bb * 1600;
        out[NPRED + a] = (t / NPAIR == bb) ? 1.0f : 0.0f;
    }

    const int wave = tid >> 6;      // 0..3
    const int lane = tid & 63;
    const int quad = lane >> 4;
    const int ocl  = lane & 15;

    // ---- build f16 im2col sX[obj][pos][k] directly from global.
    // unit u = obj*384 + pos*4 + subk; subk = tid&3 invariant under += 256.
    // k = subk*8+j; k==27 -> 1.0 (bias partner), k>27 -> 0, OOB -> 0.
    // 16B chunk index is XOR-swizzled with (pos>>1)&3 to kill the 8-way
    // bank conflict on the strided ds_read_b128 fragment reads.
    // (verified round 2: SQ_LDS_BANK_CONFLICT 1.97M -> 0)
    {
        const int subk = tid & 3;
        int koff[8], khv[8], kwv[8];
        float padf[8];
        bool kval[8];
        #pragma unroll
        for (int j = 0; j < 8; ++j) {
            int k = subk * 8 + j;
            if (k < 27) {
                int ci = k / 9;
                int r9 = k - ci * 9;
                int kh = r9 / 3;
                int kw = r9 - kh * 3;
                koff[j] = ci * (IMG_H * IMG_W) + kh * IMG_W + kw;
                khv[j] = kh; kwv[j] = kw; kval[j] = true; padf[j] = 0.f;
            } else {
                koff[j] = 0; khv[j] = 0; kwv[j] = 0; kval[j] = false;
                padf[j] = (k == 27) ? 1.0f : 0.f;
            }
        }
        for (int u = tid; u < X_UNITS; u += 256) {
            int pl  = (u >> 2) % NPOS;
            int obj = u / (NPOS * 4);
            int rl  = (pl >= 48) ? 1 : 0;
            int pc  = pl - rl * 48;
            int gr0 = R0 + 2 * rl;
            int gc0 = 2 * pc;
            const float* gp = g + obj * (CIN * IMG_H * IMG_W) + gr0 * IMG_W + gc0;
            float fv[8];
            #pragma unroll
            for (int j = 0; j < 8; ++j) {
                float v = padf[j];
                if (kval[j] && (gr0 + khv[j] < IMG_H) && (gc0 + kwv[j] < IMG_W))
                    v = gp[koff[j]];
                fv[j] = v;
            }
            uint4_ w4;
            w4.x = __builtin_bit_cast(unsigned int, __builtin_amdgcn_cvt_pkrtz(fv[0], fv[1]));
            w4.y = __builtin_bit_cast(unsigned int, __builtin_amdgcn_cvt_pkrtz(fv[2], fv[3]));
            w4.z = __builtin_bit_cast(unsigned int, __builtin_amdgcn_cvt_pkrtz(fv[4], fv[5]));
            w4.w = __builtin_bit_cast(unsigned int, __builtin_amdgcn_cvt_pkrtz(fv[6], fv[7]));
            int swk = subk ^ ((pl >> 1) & 3);
            *(uint4_*)&sX32[(size_t)(obj * (NPOS * 16) + pl * 16 + swk * 4)] = w4;
        }
    }

    __syncthreads();

    const size_t tbase = ((((size_t)src * BQ + b) * NRG + rg) * NPAIR) * 8;

    // Each wave processes two oc-tiles against the shared LDS tile.
    for (int half = 0; half < 2; ++half) {
        run_mt(sX32, conv_w, conv_b, w2, T, wave + 4 * half, quad, ocl, lane, tbase);
    }
}

// predicates: 4 threads per output, each sums 4 rowgroups via float2 loads,
// then a 2-level shfl combine. 51200 threads = 200 blocks.
__global__ __launch_bounds__(256) void pred_kernel(
    const float* __restrict__ T,
    const float* __restrict__ b2,
    const float* __restrict__ temp,
    float* __restrict__ out)
{
    int gid = blockIdx.x * blockDim.x + threadIdx.x;
    int idx = gid >> 2;
    int h   = gid & 3;
    if (idx >= NPRED) return;
    int p   = idx & 3;
    int t   = (idx >> 2) % 1600;
    int src = idx / 6400;
    int bb  = t / NPAIR;
    int pr  = t - bb * NPAIR;
    const float* base = T + ((((size_t)src * BQ + bb) * NRG) * NPAIR + pr) * 8 + 2 * p;
    float sum = 0.f;
    #pragma unroll
    for (int r = 0; r < 4; ++r) {
        int rgi = h * 4 + r;
        float2_ v = *(const float2_*)&base[(size_t)rgi * NPAIR * 8];
        sum += v[0] + v[1];
    }
    sum += __shfl_xor(sum, 1, 64);
    sum += __shfl_xor(sum, 2, 64);
    if (h == 0) {
        float logit = sum * (1.0f / (OH * OW)) + b2[p];
        float x = logit / temp[0];
        out[idx] = 1.0f / (1.0f + expf(-x));
    }
}

extern "C" void kernel_launch(void* const* d_in, const int* in_sizes, int n_in,
                              void* d_out, int out_size, void* d_ws, size_t ws_size,
                              hipStream_t stream)
{
    const float* state      = (const float*)d_in[0];
    const float* state_next = (const float*)d_in[1];
    const float* conv_w     = (const float*)d_in[2];
    const float* conv_b     = (const float*)d_in[3];
    const float* w2         = (const float*)d_in[4];
    const float* b2         = (const float*)d_in[5];
    // d_in[6] = n_obj (always 5)
    const float* temp       = (const float*)d_in[7];

    float* out = (float*)d_out;
    float* T   = (float*)d_ws;              // [2][64][16][25][8] floats = 1.64 MB

    dim3 grid1(NRG, BQ, 2);                 // 2048 blocks x 256 threads
    conv_pair_mfma<<<grid1, 256, 0, stream>>>(state, state_next, conv_w, conv_b,
                                              w2, T, out);

    pred_kernel<<<(NPRED * 4 + 255) / 256, 256, 0, stream>>>(T, b2, temp, out);
}

// Round 6
// 152.315 us; speedup vs baseline: 1.9118x; 1.9118x over previous
//
#include <hip/hip_runtime.h>
#include <math.h>

// Problem constants
#define BQ 64
#define NOBJ 5
#define CIN 3
#define IMG_H 64
#define IMG_W 96
#define OH 32
#define OW 48
#define NPAIR 25
#define PP 4
#define CONV_OUT 32

// Tiling: each block = (src, b, rowgroup of 2 output rows); 512 threads = 8 waves
#define NRG 16                          // 32 output rows / 2
#define NPOS 96                         // 2 output rows x 48 cols
#define XK 32                           // padded K (27 real + bias + zeros)
#define X_U32 (NOBJ * NPOS * XK / 2)    // 7680 u32 = 30.7 KB (f16 im2col)
#define X_UNITS (NOBJ * NPOS * 4)       // 1920 8-elem units

#define NPRED (2 * 1600 * PP)           // 12800
#define ADJ_N (BQ * 1600)               // 102400

typedef __fp16   h2 __attribute__((ext_vector_type(2)));     // cvt_pkrtz result type
typedef _Float16 half8 __attribute__((ext_vector_type(8)));  // MFMA A/B operand
typedef float    float4_ __attribute__((ext_vector_type(4)));
typedef float    float2_ __attribute__((ext_vector_type(2)));
typedef unsigned int uint4_ __attribute__((ext_vector_type(4)));

// T[src][b][rg][pair][mt]; mt = 16-oc tile 0..7 (p = mt>>1). Fully written,
// no memset, no atomics. src==1 blocks also write the adj mask.
//
// HISTORY (keep): round 2/3 showed __launch_bounds__(512,4) acts as a 64-VGPR
// cap on this toolchain -> 448 MB scratch spill. Rounds 4/5 showed the
// reduce-MFMA epilogue (4 regs/pair x 25 pairs) always loses: either spills
// or collapses occupancy to 1-2 blocks/CU. This is the round-0 fdot2
// structure (VGPR 40, ~4 blocks/CU) + verified bank-conflict swizzle.
__global__ __launch_bounds__(512) void conv_pair_mfma(
    const float* __restrict__ state,
    const float* __restrict__ state_next,
    const float* __restrict__ conv_w,
    const float* __restrict__ conv_b,
    const float* __restrict__ w2,
    float* __restrict__ T,
    float* __restrict__ out)
{
    __shared__ __align__(16) unsigned int sX32[X_U32];   // 30.7 KB f16 im2col

    const int tid = threadIdx.x;
    const int rg  = blockIdx.x;     // 0..15
    const int b   = blockIdx.y;     // 0..63
    const int src = blockIdx.z;     // 0..1

    const float* g = (src == 0 ? state : state_next)
                   + (size_t)b * NOBJ * CIN * IMG_H * IMG_W;
    const int R0 = rg * 4;          // first input row of this rowgroup

    // ---- adj mask from src==1 blocks (independent; pre-barrier) ----
    if (src == 1 && tid < 100) {
        int a  = (rg + NRG * b) * 100 + tid;     // 1024 blocks x 100 = 102400
        int bb = a / 1600;
        int t  = a - bb * 1600;
        out[NPRED + a] = (t / NPAIR == bb) ? 1.0f : 0.0f;
    }

    const int wave = tid >> 6;      // 0..7 -> mt
    const int lane = tid & 63;
    const int quad = lane >> 4;
    const int ocl  = lane & 15;

    const int mt  = wave;
    const int p   = mt >> 1;
    const int row = mt * 16 + ocl;  // this lane's conv_w row (oc)

    // ---- per-lane weights as f16 (global loads issue early, overlap staging)
    half8 wa, wb;
    #pragma unroll
    for (int j = 0; j < 8; ++j) {
        int k = quad * 8 + j;
        float va = 0.f, vb = 0.f;
        if (k < 27) {
            va = conv_w[row * 54 + k];
            vb = conv_w[row * 54 + 27 + k];
        } else if (k == 27) {
            va = conv_b[row];       // bias pairs with 1.0 lane in X
        }
        wa[j] = (_Float16)va;
        wb[j] = (_Float16)vb;
    }
    h2 w2h01, w2h23;
    {
        const float* wp = w2 + p * CONV_OUT + (mt & 1) * 16 + quad * 4;
        w2h01 = __builtin_amdgcn_cvt_pkrtz(wp[0], wp[1]);
        w2h23 = __builtin_amdgcn_cvt_pkrtz(wp[2], wp[3]);
    }

    // ---- build f16 im2col sX[obj][pos][k] directly from global.
    // unit u = obj*384 + pos*4 + subk; subk = tid&3 invariant under += 512.
    // k = subk*8+j; k==27 -> 1.0 (bias partner), k>27 -> 0, OOB -> 0.
    // 16B chunk index is XOR-swizzled with (pos>>1)&3 to kill the 8-way
    // bank conflict on the strided ds_read_b128 fragment reads.
    // (verified rounds 2-5: SQ_LDS_BANK_CONFLICT 1.97M -> 0, numerics intact)
    {
        const int subk = tid & 3;
        int koff[8], khv[8], kwv[8];
        float padf[8];
        bool kval[8];
        #pragma unroll
        for (int j = 0; j < 8; ++j) {
            int k = subk * 8 + j;
            if (k < 27) {
                int ci = k / 9;
                int r9 = k - ci * 9;
                int kh = r9 / 3;
                int kw = r9 - kh * 3;
                koff[j] = ci * (IMG_H * IMG_W) + kh * IMG_W + kw;
                khv[j] = kh; kwv[j] = kw; kval[j] = true; padf[j] = 0.f;
            } else {
                koff[j] = 0; khv[j] = 0; kwv[j] = 0; kval[j] = false;
                padf[j] = (k == 27) ? 1.0f : 0.f;
            }
        }
        for (int u = tid; u < X_UNITS; u += 512) {
            int pl  = (u >> 2) % NPOS;
            int obj = u / (NPOS * 4);
            int rl  = (pl >= 48) ? 1 : 0;
            int pc  = pl - rl * 48;
            int gr0 = R0 + 2 * rl;
            int gc0 = 2 * pc;
            const float* gp = g + obj * (CIN * IMG_H * IMG_W) + gr0 * IMG_W + gc0;
            float fv[8];
            #pragma unroll
            for (int j = 0; j < 8; ++j) {
                float v = padf[j];
                if (kval[j] && (gr0 + khv[j] < IMG_H) && (gc0 + kwv[j] < IMG_W))
                    v = gp[koff[j]];
                fv[j] = v;
            }
            uint4_ w4;
            w4.x = __builtin_bit_cast(unsigned int, __builtin_amdgcn_cvt_pkrtz(fv[0], fv[1]));
            w4.y = __builtin_bit_cast(unsigned int, __builtin_amdgcn_cvt_pkrtz(fv[2], fv[3]));
            w4.z = __builtin_bit_cast(unsigned int, __builtin_amdgcn_cvt_pkrtz(fv[4], fv[5]));
            w4.w = __builtin_bit_cast(unsigned int, __builtin_amdgcn_cvt_pkrtz(fv[6], fv[7]));
            int swk = subk ^ ((pl >> 1) & 3);
            *(uint4_*)&sX32[(size_t)(obj * (NPOS * 16) + pl * 16 + swk * 4)] = w4;
        }
    }

    __syncthreads();

    const float4_ zero4 = {0.f, 0.f, 0.f, 0.f};
    const h2 hz = {(__fp16)0.f, (__fp16)0.f};

    float acc[NPAIR];
    #pragma unroll
    for (int q = 0; q < NPAIR; ++q) acc[q] = 0.f;

    #pragma unroll
    for (int nt = 0; nt < 6; ++nt) {    // 2 rows x 3 col-tiles of 16
        const int rl  = nt / 3;
        const int c0  = (nt - rl * 3) * 16;
        const int pos = rl * 48 + c0 + ocl;
        const int sw  = (pos >> 1) & 3;
        const int sbase = pos * 16 + ((quad ^ sw) << 2);

        half8 xf[NOBJ];
        h2 ah01[NOBJ], ah23[NOBJ];
        #pragma unroll
        for (int obj = 0; obj < NOBJ; ++obj) {
            xf[obj] = *(const half8*)&sX32[sbase + obj * (NPOS * 16)];
            float4_ a = __builtin_amdgcn_mfma_f32_16x16x32_f16(wa, xf[obj], zero4, 0, 0, 0);
            ah01[obj] = __builtin_amdgcn_cvt_pkrtz(a[0], a[1]);
            ah23[obj] = __builtin_amdgcn_cvt_pkrtz(a[2], a[3]);
        }

        #pragma unroll
        for (int jo = 0; jo < NOBJ; ++jo) {
            float4_ bq = __builtin_amdgcn_mfma_f32_16x16x32_f16(wb, xf[jo], zero4, 0, 0, 0);
            h2 bh01 = __builtin_amdgcn_cvt_pkrtz(bq[0], bq[1]);
            h2 bh23 = __builtin_amdgcn_cvt_pkrtz(bq[2], bq[3]);
            #pragma unroll
            for (int i = 0; i < NOBJ; ++i) {
                h2 s0 = ah01[i] + bh01;                        // v_pk_add_f16
                h2 s1 = ah23[i] + bh23;
                s0 = __builtin_elementwise_max(s0, hz);        // v_pk_max_f16
                s1 = __builtin_elementwise_max(s1, hz);
                float t0 = __builtin_amdgcn_fdot2(s0, w2h01, acc[i * NOBJ + jo], false);
                acc[i * NOBJ + jo] = __builtin_amdgcn_fdot2(s1, w2h23, t0, false);
            }
        }
    }

    // ---- wave-reduce each pair across 64 lanes; direct store (no atomics) ----
    float myv = 0.f;
    #pragma unroll
    for (int q = 0; q < NPAIR; ++q) {
        float rr = acc[q];
        #pragma unroll
        for (int off = 32; off > 0; off >>= 1)
            rr += __shfl_xor(rr, off, 64);
        if (lane == q) myv = rr;
    }
    if (lane < NPAIR)
        T[((((size_t)src * BQ + b) * NRG + rg) * NPAIR + lane) * 8 + mt] = myv;
}

// predicates: 4 threads per output, each sums 4 rowgroups via float2 loads,
// then a 2-level shfl combine. 51200 threads = 200 blocks.
__global__ __launch_bounds__(256) void pred_kernel(
    const float* __restrict__ T,
    const float* __restrict__ b2,
    const float* __restrict__ temp,
    float* __restrict__ out)
{
    int gid = blockIdx.x * blockDim.x + threadIdx.x;
    int idx = gid >> 2;
    int h   = gid & 3;
    if (idx >= NPRED) return;
    int p   = idx & 3;
    int t   = (idx >> 2) % 1600;
    int src = idx / 6400;
    int bb  = t / NPAIR;
    int pr  = t - bb * NPAIR;
    const float* base = T + ((((size_t)src * BQ + bb) * NRG) * NPAIR + pr) * 8 + 2 * p;
    float sum = 0.f;
    #pragma unroll
    for (int r = 0; r < 4; ++r) {
        int rgi = h * 4 + r;
        float2_ v = *(const float2_*)&base[(size_t)rgi * NPAIR * 8];
        sum += v[0] + v[1];
    }
    sum += __shfl_xor(sum, 1, 64);
    sum += __shfl_xor(sum, 2, 64);
    if (h == 0) {
        float logit = sum * (1.0f / (OH * OW)) + b2[p];
        float x = logit / temp[0];
        out[idx] = 1.0f / (1.0f + expf(-x));
    }
}

extern "C" void kernel_launch(void* const* d_in, const int* in_sizes, int n_in,
                              void* d_out, int out_size, void* d_ws, size_t ws_size,
                              hipStream_t stream)
{
    const float* state      = (const float*)d_in[0];
    const float* state_next = (const float*)d_in[1];
    const float* conv_w     = (const float*)d_in[2];
    const float* conv_b     = (const float*)d_in[3];
    const float* w2         = (const float*)d_in[4];
    const float* b2         = (const float*)d_in[5];
    // d_in[6] = n_obj (always 5)
    const float* temp       = (const float*)d_in[7];

    float* out = (float*)d_out;
    float* T   = (float*)d_ws;              // [2][64][16][25][8] floats = 1.64 MB

    dim3 grid1(NRG, BQ, 2);                 // 2048 blocks x 512 threads
    conv_pair_mfma<<<grid1, 512, 0, stream>>>(state, state_next, conv_w, conv_b,
                                              w2, T, out);

    pred_kernel<<<(NPRED * 4 + 255) / 256, 256, 0, stream>>>(T, b2, temp, out);
}